// Round 8
// baseline (74.159 us; speedup 1.0000x reference)
//
#include <hip/hip_runtime.h>

// CircleLoss, B=8192, D=128, fp32 in, scalar fp32 out.
// 2-kernel pipeline:
//  K1: L2-normalize rows -> bf16 (+ diagonal dot, + zero counters)
//  K2: fused bf16-MFMA sim GEMM + masked-LSE partials, with cascaded
//      last-arriver finalize (rowfin per row-group, then fixed-order mean).

#define B_N 8192
#define D_K 128
#define MARGIN 0.25f
#define M2 (MARGIN * MARGIN)
#define GAMMA 256.0f

#define BM 256          // rows per block (A panel)
#define BN 128          // cols per subtile
#define NCH 8           // column chunks (grid.x)
#define CPB (B_N / NCH) // 1024 columns per chunk
#define NSUB (CPB / BN) // 8 subtiles per chunk
#define NYG (B_N / BM)  // 32 row-groups

typedef __attribute__((ext_vector_type(8))) short short8;
typedef __attribute__((ext_vector_type(4))) float f32x4;

__device__ __forceinline__ unsigned short f2bf(float x) {
  // round-to-nearest-even fp32 -> bf16
  unsigned u = __float_as_uint(x);
  u += 0x7FFFu + ((u >> 16) & 1u);
  return (unsigned short)(u >> 16);
}

__device__ __forceinline__ void gload_lds16(const void* gsrc, void* ldst) {
  // async 16B/lane global->LDS; LDS dest is wave-uniform base + lane*16
  __builtin_amdgcn_global_load_lds(
      (const __attribute__((address_space(1))) void*)gsrc,
      (__attribute__((address_space(3))) void*)ldst, 16, 0, 0);
}

// ------- kernel 1: L2-normalize rows -> bf16, plus diagonal dot -------
// One wave per row index r: lanes 0-31 handle a[r], lanes 32-63 handle b[r]
// (float4 each). After normalize, cross-half shfl gives diag[r]=dot(a_n,b_n).
// Block 0 also zeroes the finalize counters (fresh every launch/replay).
__global__ __launch_bounds__(256) void norm_diag_kernel(
    const float* __restrict__ a, const float* __restrict__ b,
    unsigned short* __restrict__ abf, unsigned short* __restrict__ bbf,
    float* __restrict__ diag, int* __restrict__ cnt) {
  if (blockIdx.x == 0 && threadIdx.x < NYG + 1) cnt[threadIdx.x] = 0;
  int wave = threadIdx.x >> 6, lane = threadIdx.x & 63;
  int r = blockIdx.x * 4 + wave;  // 0..B_N-1
  int half = lane >> 5, l32 = lane & 31;
  const float* src = half ? b : a;
  unsigned short* dst = half ? bbf : abf;

  float4 v = ((const float4*)(src + (size_t)r * D_K))[l32];
  float ss = v.x * v.x + v.y * v.y + v.z * v.z + v.w * v.w;
  #pragma unroll
  for (int m = 16; m >= 1; m >>= 1) ss += __shfl_xor(ss, m);  // within half
  float inv = 1.0f / fmaxf(sqrtf(ss), 1e-12f);
  float n0 = v.x * inv, n1 = v.y * inv, n2 = v.z * inv, n3 = v.w * inv;

  ushort4 o = {f2bf(n0), f2bf(n1), f2bf(n2), f2bf(n3)};
  ((ushort4*)(dst + (size_t)r * D_K))[l32] = o;

  // diagonal dot: pair with same l32 in the other half
  float d = n0 * __shfl_xor(n0, 32) + n1 * __shfl_xor(n1, 32) +
            n2 * __shfl_xor(n2, 32) + n3 * __shfl_xor(n3, 32);
  #pragma unroll
  for (int m = 16; m >= 1; m >>= 1) d += __shfl_xor(d, m);
  if (lane == 0) diag[r] = d;
}

// ---------- kernel 2: fused sim GEMM + LSE partials + cascaded finalize ----
// grid = (NCH, NYG), block = 512 (8 waves 4x2; each wave owns a 64x64 output
// quadrant as 4x4 fragments of 16x16). C = A_n * B_n^T via 16x16x32 MFMA.
// A (256 rows) staged via the two B LDS buffers, hoisted to 64 VGPRs/lane;
// both buffers then double-buffer the B subtiles. XOR-swizzled 16B granules.
// Epilogue accumulates sum(exp(logit_neg)-1) with uniform __any skip.
// Tail: 8th chunk-arriver per row-group does rowfin inline; 32nd row-group
// finisher sums 32 partials in fixed order -> out.
__global__ __launch_bounds__(512, 2) void simlse_fused_kernel(
    const unsigned short* __restrict__ abf, const unsigned short* __restrict__ bbf,
    const float* __restrict__ diag, float* __restrict__ partS,
    float* __restrict__ bpart, int* __restrict__ cnt, float* __restrict__ out) {
  __shared__ __align__(16) unsigned short BB[2][BN * D_K];  // 2 x 32 KB
  __shared__ float sred[BM][2];  // cross-wave (wc) row-sum combine
  __shared__ float redf[8];
  __shared__ int amlast;

  const int tid = threadIdx.x;
  const int wave = tid >> 6, lane = tid & 63;
  const int r16 = lane & 15, kq = lane >> 4;
  const int wr = wave >> 1, wc = wave & 1;  // wr 0..3, wc 0..1
  const int rowBase = blockIdx.y * BM;
  const int chunk = blockIdx.x;

  // stage A rows [0,128) -> BB[0], rows [128,256) -> BB[1] (swizzled)
  #pragma unroll
  for (int half = 0; half < 2; ++half) {
    const unsigned short* srcA = abf + (size_t)(rowBase + half * 128) * D_K;
    #pragma unroll
    for (int it = 0; it < 4; ++it) {
      int gb = it * 512 + wave * 64;  // wave-uniform granule base
      int g = gb + lane;
      int row = g >> 4, sl = g & 15;
      int sls = sl ^ (row & 7);
      gload_lds16(srcA + (size_t)row * D_K + sls * 8, &BB[half][gb * 8]);
    }
  }
  __syncthreads();  // vmcnt drained: A halves ready

  // hoist A-fragments into registers (reused by all 8 subtiles)
  short8 af[4][4];  // [mi][ks]
  {
    const unsigned short* Abuf = BB[wr >> 1];
    const int rbase = (wr & 1) * 64;  // local row base within the half
    #pragma unroll
    for (int mi = 0; mi < 4; ++mi) {
      int row = rbase + mi * 16 + r16;
      #pragma unroll
      for (int ks = 0; ks < 4; ++ks) {
        int slot = (ks * 4 + kq) ^ (row & 7);
        af[mi][ks] = *(const short8*)&Abuf[row * D_K + slot * 8];
      }
    }
  }
  __syncthreads();  // all waves done reading A -> buffers reusable

  // stage B subtile 0 -> BB[0], subtile 1 -> BB[1]
  #pragma unroll
  for (int h = 0; h < 2; ++h) {
    const unsigned short* srcB = bbf + (size_t)(chunk * CPB + h * BN) * D_K;
    #pragma unroll
    for (int it = 0; it < 4; ++it) {
      int gb = it * 512 + wave * 64;
      int g = gb + lane;
      int row = g >> 4, sl = g & 15;
      int sls = sl ^ (row & 7);
      gload_lds16(srcB + (size_t)row * D_K + sls * 8, &BB[h][gb * 8]);
    }
  }
  __syncthreads();  // B0, B1 ready

  float Ssum[4][4];  // [mi][reg] per-row running sum of (exp(logit_neg)-1)
  #pragma unroll
  for (int mi = 0; mi < 4; ++mi)
    #pragma unroll
    for (int r = 0; r < 4; ++r) Ssum[mi][r] = 0.0f;

  #pragma unroll 2
  for (int st = 0; st < NSUB; ++st) {
    const unsigned short* cb = BB[st & 1];  // current B buffer

    f32x4 acc[4][4];
    const f32x4 z4 = {0.f, 0.f, 0.f, 0.f};
    #pragma unroll
    for (int mi = 0; mi < 4; ++mi)
      #pragma unroll
      for (int ni = 0; ni < 4; ++ni) acc[mi][ni] = z4;

    #pragma unroll
    for (int ks = 0; ks < 4; ++ks) {
      short8 bf[4];
      #pragma unroll
      for (int ni = 0; ni < 4; ++ni) {
        int row = wc * 64 + ni * 16 + r16;
        int slot = (ks * 4 + kq) ^ (row & 7);
        bf[ni] = *(const short8*)&cb[row * D_K + slot * 8];
      }
      #pragma unroll
      for (int mi = 0; mi < 4; ++mi)
        #pragma unroll
        for (int ni = 0; ni < 4; ++ni)
          acc[mi][ni] = __builtin_amdgcn_mfma_f32_16x16x32_bf16(
              af[mi][ks], bf[ni], acc[mi][ni], 0, 0, 0);
    }

    // epilogue: logit = (s>m) ? GAMMA*(s^2-m^2) : 0; accumulate exp(logit)-1.
    #pragma unroll
    for (int mi = 0; mi < 4; ++mi)
      #pragma unroll
      for (int ni = 0; ni < 4; ++ni) {
        f32x4 v = acc[mi][ni];
        float mx = fmaxf(fmaxf(v[0], v[1]), fmaxf(v[2], v[3]));
        if (__any(mx > MARGIN)) {
          #pragma unroll
          for (int r = 0; r < 4; ++r) {
            float s = v[r];
            float t = fmaf(s, s, -M2);
            float z = (s > MARGIN) ? GAMMA * t : 0.0f;
            Ssum[mi][r] += __expf(z) - 1.0f;  // exactly 0 when z==0
          }
        }
      }

    __syncthreads();  // ends reads of cb; drains next buffer's prefetch

    if (st + 2 < NSUB) {  // prefetch subtile st+2 into the buffer just freed
      const unsigned short* srcB =
          bbf + (size_t)(chunk * CPB + (st + 2) * BN) * D_K;
      unsigned short* dstB = (unsigned short*)BB[st & 1];
      #pragma unroll
      for (int it = 0; it < 4; ++it) {
        int gb = it * 512 + wave * 64;
        int g = gb + lane;
        int row = g >> 4, sl = g & 15;
        int sls = sl ^ (row & 7);
        gload_lds16(srcB + (size_t)row * D_K + sls * 8, &dstB[gb * 8]);
      }
    }
  }

  // reduce Ssum across the 16 lanes sharing each output row, combine wc=0/1.
  #pragma unroll
  for (int mi = 0; mi < 4; ++mi)
    #pragma unroll
    for (int r = 0; r < 4; ++r) {
      float v = Ssum[mi][r];
      v += __shfl_xor(v, 1);
      v += __shfl_xor(v, 2);
      v += __shfl_xor(v, 4);
      v += __shfl_xor(v, 8);
      if (r16 == 0) sred[wr * 64 + mi * 16 + kq * 4 + r][wc] = v;
    }
  __syncthreads();
  if (tid < BM)
    partS[(size_t)chunk * B_N + rowBase + tid] = sred[tid][0] + sred[tid][1];

  // ---- cascaded finalize ----
  __threadfence();  // release this block's partS writes (device scope)
  if (tid == 0)
    amlast = (__hip_atomic_fetch_add(&cnt[blockIdx.y], 1, __ATOMIC_ACQ_REL,
                                     __HIP_MEMORY_SCOPE_AGENT) == NCH - 1);
  __syncthreads();
  if (!amlast) return;

  // 8th arriver for this row-group: rowfin for rows [rowBase, rowBase+BM)
  float loss = 0.0f;
  if (tid < BM) {
    int row = rowBase + tid;
    float S = 0.0f;
    #pragma unroll
    for (int c = 0; c < NCH; ++c)
      S += __hip_atomic_load(&partS[(size_t)c * B_N + row], __ATOMIC_RELAXED,
                             __HIP_MEMORY_SCOPE_AGENT);
    float sd = diag[row];
    float zd = (sd > MARGIN) ? GAMMA * fmaf(sd, sd, -M2) : 0.0f;
    float ed = __expf(zd);
    // sum over off-diag of exp(logit_neg) = B + sum(e-1 over all) - e_diag
    float lneg = __logf((float)B_N + S - ed);
    float lpos = -GAMMA * fmaxf((1.0f - MARGIN) - sd, 0.0f) * (sd - MARGIN);
    float x = lpos + lneg;
    loss = fmaxf(x, 0.0f) + log1pf(__expf(-fabsf(x)));  // softplus
  }
  #pragma unroll
  for (int m = 32; m >= 1; m >>= 1) loss += __shfl_xor(loss, m);
  if (lane == 0) redf[wave] = loss;
  __syncthreads();
  if (tid == 0) {
    float t = 0.0f;
    #pragma unroll
    for (int i = 0; i < 8; ++i) t += redf[i];
    bpart[blockIdx.y] = t;
    __threadfence();  // release bpart before arrival
    int old = __hip_atomic_fetch_add(&cnt[NYG], 1, __ATOMIC_ACQ_REL,
                                     __HIP_MEMORY_SCOPE_AGENT);
    if (old == NYG - 1) {  // last row-group: deterministic fixed-order sum
      float tot = 0.0f;
      #pragma unroll
      for (int j = 0; j < NYG; ++j)
        tot += __hip_atomic_load(&bpart[j], __ATOMIC_RELAXED,
                                 __HIP_MEMORY_SCOPE_AGENT);
      out[0] = tot * (1.0f / B_N);
    }
  }
}

extern "C" void kernel_launch(void* const* d_in, const int* in_sizes, int n_in,
                              void* d_out, int out_size, void* d_ws, size_t ws_size,
                              hipStream_t stream) {
  const float* a = (const float*)d_in[0];
  const float* b = (const float*)d_in[1];
  float* out = (float*)d_out;

  char* w = (char*)d_ws;
  unsigned short* abf = (unsigned short*)w;                              // 2 MB
  unsigned short* bbf = (unsigned short*)(w + (size_t)B_N * D_K * 2);    // 2 MB
  float* partS = (float*)(w + (size_t)B_N * D_K * 4);                    // 256 KB
  float* diag = partS + (size_t)NCH * B_N;                               // 32 KB
  float* bpart = diag + B_N;                                             // 128 B
  int* cnt = (int*)(bpart + NYG);                                        // 33 ints

  norm_diag_kernel<<<B_N / 4, 256, 0, stream>>>(a, b, abf, bbf, diag, cnt);
  simlse_fused_kernel<<<dim3(NCH, NYG), 512, 0, stream>>>(
      abf, bbf, diag, partS, bpart, cnt, out);
}

// Round 9
// 57.058 us; speedup vs baseline: 1.2997x; 1.2997x over previous
//
#include <hip/hip_runtime.h>

// CircleLoss, B=8192, D=128, fp32 in, scalar fp32 out.
// Pipeline: (1) normalize->bf16 + fused diagonal dot, (2) fused bf16-MFMA
// sim GEMM + masked-LSE partials (A-frags in regs, SINGLE-buffer B staging at
// 3 blocks/CU - TLP instead of double-buffering), (3) rowfin, (4) mean.

#define B_N 8192
#define D_K 128
#define MARGIN 0.25f
#define M2 (MARGIN * MARGIN)
#define GAMMA 256.0f

#define BM 128          // rows per block (A panel)
#define BN 128          // cols per subtile
#define NCH 8           // column chunks (grid.x)
#define CPB (B_N / NCH) // 1024 columns per chunk
#define NSUB (CPB / BN) // 8 subtiles per chunk
#define NROWBLK 32      // rowfin blocks

typedef __attribute__((ext_vector_type(8))) short short8;
typedef __attribute__((ext_vector_type(4))) float f32x4;

__device__ __forceinline__ unsigned short f2bf(float x) {
  // round-to-nearest-even fp32 -> bf16
  unsigned u = __float_as_uint(x);
  u += 0x7FFFu + ((u >> 16) & 1u);
  return (unsigned short)(u >> 16);
}

__device__ __forceinline__ void gload_lds16(const void* gsrc, void* ldst) {
  // async 16B/lane global->LDS; LDS dest is wave-uniform base + lane*16
  __builtin_amdgcn_global_load_lds(
      (const __attribute__((address_space(1))) void*)gsrc,
      (__attribute__((address_space(3))) void*)ldst, 16, 0, 0);
}

// ------- kernel 1: L2-normalize rows -> bf16, plus diagonal dot -------
// One wave per row index r: lanes 0-31 handle a[r], lanes 32-63 handle b[r]
// (float4 each). After normalize, cross-half shfl gives diag[r]=dot(a_n,b_n).
__global__ __launch_bounds__(256) void norm_diag_kernel(
    const float* __restrict__ a, const float* __restrict__ b,
    unsigned short* __restrict__ abf, unsigned short* __restrict__ bbf,
    float* __restrict__ diag) {
  int wave = threadIdx.x >> 6, lane = threadIdx.x & 63;
  int r = blockIdx.x * 4 + wave;  // 0..B_N-1
  int half = lane >> 5, l32 = lane & 31;
  const float* src = half ? b : a;
  unsigned short* dst = half ? bbf : abf;

  float4 v = ((const float4*)(src + (size_t)r * D_K))[l32];
  float ss = v.x * v.x + v.y * v.y + v.z * v.z + v.w * v.w;
  #pragma unroll
  for (int m = 16; m >= 1; m >>= 1) ss += __shfl_xor(ss, m);  // within half
  float inv = 1.0f / fmaxf(sqrtf(ss), 1e-12f);
  float n0 = v.x * inv, n1 = v.y * inv, n2 = v.z * inv, n3 = v.w * inv;

  ushort4 o = {f2bf(n0), f2bf(n1), f2bf(n2), f2bf(n3)};
  ((ushort4*)(dst + (size_t)r * D_K))[l32] = o;

  // diagonal dot: pair with same l32 in the other half
  float d = n0 * __shfl_xor(n0, 32) + n1 * __shfl_xor(n1, 32) +
            n2 * __shfl_xor(n2, 32) + n3 * __shfl_xor(n3, 32);
  #pragma unroll
  for (int m = 16; m >= 1; m >>= 1) d += __shfl_xor(d, m);
  if (lane == 0) diag[r] = d;
}

// ---------- kernel 2: fused sim GEMM (bf16 MFMA) + neg-LSE partials ----------
// grid = (NCH, B_N/BM), block = 256 (4 waves, each owns a 64x64 output quadrant
// as 4x4 fragments of 16x16). C = A_n * B_n^T via mfma_f32_16x16x32_bf16.
// SINGLE 32KB B buffer: per subtile {barrier; stage; barrier; compute}.
// With ~170 VGPR (launch_bounds 256,3) and 33KB LDS -> 3 blocks/CU; the
// other blocks' compute covers each block's staging drain (TLP pipelining,
// m97-ladder pattern). A staged through the same buffer once, hoisted to
// 64 VGPRs. XOR-swizzled 16B granules (pre-swizzled global source), reads
// slot = g ^ (row&7).
// Epilogue accumulates sum(exp(logit_neg)-1): zero for reg-quads with all
// s<=m (uniform __any skip). Diagonal handled in kernels 1/3.
__global__ __launch_bounds__(256, 3) void simlse_kernel(
    const unsigned short* __restrict__ abf, const unsigned short* __restrict__ bbf,
    float* __restrict__ partS) {
  __shared__ __align__(16) unsigned short Bs[BN * D_K];  // 32 KB
  __shared__ float sred[BM][2];  // cross-wave (wc) row-sum combine

  const int tid = threadIdx.x;
  const int wave = tid >> 6, lane = tid & 63;
  const int r16 = lane & 15, kq = lane >> 4;
  const int wr = wave >> 1, wc = wave & 1;
  const int rowBase = blockIdx.y * BM;
  const int chunk = blockIdx.x;

  // per-lane staging source offsets (element units) within a 128x128 tile
  int stageOff[8];
  #pragma unroll
  for (int it = 0; it < 8; ++it) {
    int g = it * 256 + wave * 64 + lane;
    int row = g >> 4, sl = g & 15;
    stageOff[it] = row * D_K + (sl ^ (row & 7)) * 8;
  }

  // stage A tile -> Bs (swizzled), then hoist A-fragments to registers
  {
    const unsigned short* srcA = abf + (size_t)rowBase * D_K;
    #pragma unroll
    for (int it = 0; it < 8; ++it)
      gload_lds16(srcA + stageOff[it], &Bs[(it * 256 + wave * 64) * 8]);
  }
  __syncthreads();  // vmcnt drained: A ready

  short8 af[4][4];  // [mi][ks], reused by all 8 subtiles
  #pragma unroll
  for (int mi = 0; mi < 4; ++mi) {
    int row = wr * 64 + mi * 16 + r16;
    #pragma unroll
    for (int ks = 0; ks < 4; ++ks) {
      int slot = (ks * 4 + kq) ^ (row & 7);
      af[mi][ks] = *(const short8*)&Bs[row * D_K + slot * 8];
    }
  }

  float Ssum[4][4];  // [mi][reg] per-row running sum of (exp(logit_neg)-1)
  #pragma unroll
  for (int mi = 0; mi < 4; ++mi)
    #pragma unroll
    for (int r = 0; r < 4; ++r) Ssum[mi][r] = 0.0f;

  for (int st = 0; st < NSUB; ++st) {
    __syncthreads();  // all waves done reading Bs (af hoist / prev subtile)
    {
      const unsigned short* srcB = bbf + (size_t)(chunk * CPB + st * BN) * D_K;
      #pragma unroll
      for (int it = 0; it < 8; ++it)
        gload_lds16(srcB + stageOff[it], &Bs[(it * 256 + wave * 64) * 8]);
    }
    __syncthreads();  // vmcnt drained: B subtile ready

    f32x4 acc[4][4];
    const f32x4 z4 = {0.f, 0.f, 0.f, 0.f};
    #pragma unroll
    for (int mi = 0; mi < 4; ++mi)
      #pragma unroll
      for (int ni = 0; ni < 4; ++ni) acc[mi][ni] = z4;

    #pragma unroll
    for (int ks = 0; ks < 4; ++ks) {
      short8 bf[4];
      #pragma unroll
      for (int ni = 0; ni < 4; ++ni) {
        int row = wc * 64 + ni * 16 + r16;
        int slot = (ks * 4 + kq) ^ (row & 7);
        bf[ni] = *(const short8*)&Bs[row * D_K + slot * 8];
      }
      #pragma unroll
      for (int mi = 0; mi < 4; ++mi)
        #pragma unroll
        for (int ni = 0; ni < 4; ++ni)
          acc[mi][ni] = __builtin_amdgcn_mfma_f32_16x16x32_bf16(
              af[mi][ks], bf[ni], acc[mi][ni], 0, 0, 0);
    }

    // epilogue: logit = (s>m) ? GAMMA*(s^2-m^2) : 0; accumulate exp(logit)-1.
    // For unit-normal embeddings P(s>m) ~ 0.2%, so most reg-quads skip.
    #pragma unroll
    for (int mi = 0; mi < 4; ++mi)
      #pragma unroll
      for (int ni = 0; ni < 4; ++ni) {
        f32x4 v = acc[mi][ni];
        float mx = fmaxf(fmaxf(v[0], v[1]), fmaxf(v[2], v[3]));
        if (__any(mx > MARGIN)) {
          #pragma unroll
          for (int r = 0; r < 4; ++r) {
            float s = v[r];
            float t = fmaf(s, s, -M2);
            float z = (s > MARGIN) ? GAMMA * t : 0.0f;
            Ssum[mi][r] += __expf(z) - 1.0f;  // exactly 0 when z==0
          }
        }
      }
  }

  // reduce Ssum across the 16 lanes sharing each output row (same kq group),
  // then combine the two column-half waves (wc=0/1) through LDS.
  #pragma unroll
  for (int mi = 0; mi < 4; ++mi)
    #pragma unroll
    for (int r = 0; r < 4; ++r) {
      float v = Ssum[mi][r];
      v += __shfl_xor(v, 1);
      v += __shfl_xor(v, 2);
      v += __shfl_xor(v, 4);
      v += __shfl_xor(v, 8);
      if (r16 == 0) sred[wr * 64 + mi * 16 + kq * 4 + r][wc] = v;
    }
  __syncthreads();
  if (tid < BM)
    partS[(size_t)chunk * B_N + rowBase + tid] = sred[tid][0] + sred[tid][1];
}

// ------- kernel 3: per-row finalize + per-block partial sum -------
__global__ __launch_bounds__(256) void rowfin_kernel(
    const float* __restrict__ partS, const float* __restrict__ diag,
    float* __restrict__ bpart) {
  __shared__ float red[4];
  int tid = threadIdx.x, lane = tid & 63, wid = tid >> 6;
  int i = blockIdx.x * 256 + tid;
  float S = 0.0f;
  #pragma unroll
  for (int c = 0; c < NCH; ++c) S += partS[(size_t)c * B_N + i];
  float sd = diag[i];
  float zd = (sd > MARGIN) ? GAMMA * fmaf(sd, sd, -M2) : 0.0f;
  float ed = __expf(zd);
  // sum over off-diagonal of exp(logit_neg) = B + sum(e-1 over all) - e_diag
  float lneg = __logf((float)B_N + S - ed);
  float lpos = -GAMMA * fmaxf((1.0f - MARGIN) - sd, 0.0f) * (sd - MARGIN);
  float x = lpos + lneg;
  float acc = fmaxf(x, 0.0f) + log1pf(__expf(-fabsf(x)));  // softplus
  #pragma unroll
  for (int m = 32; m >= 1; m >>= 1) acc += __shfl_xor(acc, m);
  if (lane == 0) red[wid] = acc;
  __syncthreads();
  if (tid == 0) bpart[blockIdx.x] = red[0] + red[1] + red[2] + red[3];
}

// ---------------- kernel 4: mean over 32 block partials ----------------
__global__ __launch_bounds__(64) void mean_kernel(
    const float* __restrict__ bpart, float* __restrict__ out) {
  int lane = threadIdx.x;
  float v = (lane < 32) ? bpart[lane] : 0.0f;
  #pragma unroll
  for (int m = 32; m >= 1; m >>= 1) v += __shfl_xor(v, m);
  if (lane == 0) out[0] = v * (1.0f / B_N);
}

extern "C" void kernel_launch(void* const* d_in, const int* in_sizes, int n_in,
                              void* d_out, int out_size, void* d_ws, size_t ws_size,
                              hipStream_t stream) {
  const float* a = (const float*)d_in[0];
  const float* b = (const float*)d_in[1];
  float* out = (float*)d_out;

  char* w = (char*)d_ws;
  unsigned short* abf = (unsigned short*)w;                              // 2 MB
  unsigned short* bbf = (unsigned short*)(w + (size_t)B_N * D_K * 2);    // 2 MB
  float* partS = (float*)(w + (size_t)B_N * D_K * 4);                    // 256 KB
  float* diag = partS + (size_t)NCH * B_N;                               // 32 KB
  float* bpart = diag + B_N;                                             // 128 B

  norm_diag_kernel<<<B_N / 4, 256, 0, stream>>>(a, b, abf, bbf, diag);
  simlse_kernel<<<dim3(NCH, B_N / BM), 256, 0, stream>>>(abf, bbf, partS);
  rowfin_kernel<<<NROWBLK, 256, 0, stream>>>(partS, diag, bpart);
  mean_kernel<<<1, 64, 0, stream>>>(bpart, out);
}

// Round 10
// 37.172 us; speedup vs baseline: 1.9950x; 1.5350x over previous
//
#include <hip/hip_runtime.h>

// CircleLoss, B=8192, D=128, fp32 in, scalar fp32 out.
// Pipeline: (1) normalize->bf16 + fused diagonal dot, (2) fused bf16-MFMA
// sim GEMM + masked-LSE partials (BN=64 double-buffered B staging, 4
// blocks/CU occupancy, A-frags in regs), (3) rowfin, (4) mean.

#define B_N 8192
#define D_K 128
#define MARGIN 0.25f
#define M2 (MARGIN * MARGIN)
#define GAMMA 256.0f

#define BM 128          // rows per block (A panel)
#define BN 64           // cols per subtile
#define NCH 16          // column chunks (grid.x)
#define CPB (B_N / NCH) // 512 columns per chunk
#define NSUB (CPB / BN) // 8 subtiles per chunk
#define NROWBLK 32      // rowfin blocks

typedef __attribute__((ext_vector_type(8))) short short8;
typedef __attribute__((ext_vector_type(4))) float f32x4;

__device__ __forceinline__ unsigned short f2bf(float x) {
  // round-to-nearest-even fp32 -> bf16
  unsigned u = __float_as_uint(x);
  u += 0x7FFFu + ((u >> 16) & 1u);
  return (unsigned short)(u >> 16);
}

__device__ __forceinline__ void gload_lds16(const void* gsrc, void* ldst) {
  // async 16B/lane global->LDS; LDS dest is wave-uniform base + lane*16
  __builtin_amdgcn_global_load_lds(
      (const __attribute__((address_space(1))) void*)gsrc,
      (__attribute__((address_space(3))) void*)ldst, 16, 0, 0);
}

// ------- kernel 1: L2-normalize rows -> bf16, plus diagonal dot -------
// One wave per row index r: lanes 0-31 handle a[r], lanes 32-63 handle b[r]
// (float4 each). After normalize, cross-half shfl gives diag[r]=dot(a_n,b_n).
__global__ __launch_bounds__(256) void norm_diag_kernel(
    const float* __restrict__ a, const float* __restrict__ b,
    unsigned short* __restrict__ abf, unsigned short* __restrict__ bbf,
    float* __restrict__ diag) {
  int wave = threadIdx.x >> 6, lane = threadIdx.x & 63;
  int r = blockIdx.x * 4 + wave;  // 0..B_N-1
  int half = lane >> 5, l32 = lane & 31;
  const float* src = half ? b : a;
  unsigned short* dst = half ? bbf : abf;

  float4 v = ((const float4*)(src + (size_t)r * D_K))[l32];
  float ss = v.x * v.x + v.y * v.y + v.z * v.z + v.w * v.w;
  #pragma unroll
  for (int m = 16; m >= 1; m >>= 1) ss += __shfl_xor(ss, m);  // within half
  float inv = 1.0f / fmaxf(sqrtf(ss), 1e-12f);
  float n0 = v.x * inv, n1 = v.y * inv, n2 = v.z * inv, n3 = v.w * inv;

  ushort4 o = {f2bf(n0), f2bf(n1), f2bf(n2), f2bf(n3)};
  ((ushort4*)(dst + (size_t)r * D_K))[l32] = o;

  // diagonal dot: pair with same l32 in the other half
  float d = n0 * __shfl_xor(n0, 32) + n1 * __shfl_xor(n1, 32) +
            n2 * __shfl_xor(n2, 32) + n3 * __shfl_xor(n3, 32);
  #pragma unroll
  for (int m = 16; m >= 1; m >>= 1) d += __shfl_xor(d, m);
  if (lane == 0) diag[r] = d;
}

// ---------- kernel 2: fused sim GEMM (bf16 MFMA) + neg-LSE partials ----------
// grid = (NCH, B_N/BM) = (16,64) = 1024 blocks, block = 256 (4 waves; each
// wave owns a 32x64 output strip as 2x4 fragments of 16x16).
// C = A_n * B_n^T via mfma_f32_16x16x32_bf16.
// Occupancy-first design: dbuf = 2 x 16KB LDS (33KB/block) and ~110 VGPR
// (launch_bounds 256,4) -> 4 blocks/CU = 16 waves/CU, so other blocks'
// compute covers each block's staging drain. A staged once via both buffers,
// hoisted to 32 VGPRs. XOR-swizzled 16B granules (pre-swizzled global
// source), reads slot = s ^ (row&7).
// Epilogue accumulates sum(exp(logit_neg)-1): zero for reg-quads with all
// s<=m (uniform __any skip). Diagonal handled in kernels 1/3.
__global__ __launch_bounds__(256, 4) void simlse_kernel(
    const unsigned short* __restrict__ abf, const unsigned short* __restrict__ bbf,
    float* __restrict__ partS) {
  __shared__ __align__(16) unsigned short L[2][BN * D_K];  // 2 x 16 KB

  const int tid = threadIdx.x;
  const int wave = tid >> 6, lane = tid & 63;
  const int r16 = lane & 15, kq = lane >> 4;
  const int rowBase = blockIdx.y * BM;
  const int chunk = blockIdx.x;

  // per-lane staging source offsets (element units) within a 64x128 tile:
  // granule g = it*256 + tid, row = g>>4 (0..63), slot pre-swizzled.
  int stageOff[4];
  #pragma unroll
  for (int it = 0; it < 4; ++it) {
    int g = it * 256 + tid;
    int row = g >> 4, sl = g & 15;
    stageOff[it] = row * D_K + (sl ^ (row & 7)) * 8;
  }

  // stage A rows [0,64) -> L[0], rows [64,128) -> L[1] (swizzled)
  #pragma unroll
  for (int half = 0; half < 2; ++half) {
    const unsigned short* srcA = abf + (size_t)(rowBase + half * 64) * D_K;
    #pragma unroll
    for (int it = 0; it < 4; ++it)
      gload_lds16(srcA + stageOff[it], &L[half][(it * 256 + wave * 64) * 8]);
  }
  __syncthreads();  // vmcnt drained: A ready

  // hoist A-fragments into registers (reused by all subtiles)
  short8 af[2][4];  // [mi][ks]
  #pragma unroll
  for (int mi = 0; mi < 2; ++mi) {
    int row = wave * 32 + mi * 16 + r16;  // 0..127
    const unsigned short* Abuf = L[row >> 6];
    int lrow = row & 63;
    #pragma unroll
    for (int ks = 0; ks < 4; ++ks) {
      int slot = (ks * 4 + kq) ^ (lrow & 7);
      af[mi][ks] = *(const short8*)&Abuf[lrow * D_K + slot * 8];
    }
  }
  __syncthreads();  // all waves done reading A -> buffers reusable

  // stage B subtile 0 -> L[0], subtile 1 -> L[1]
  #pragma unroll
  for (int h = 0; h < 2; ++h) {
    const unsigned short* srcB = bbf + (size_t)(chunk * CPB + h * BN) * D_K;
    #pragma unroll
    for (int it = 0; it < 4; ++it)
      gload_lds16(srcB + stageOff[it], &L[h][(it * 256 + wave * 64) * 8]);
  }
  __syncthreads();  // B0, B1 ready

  float Ssum[2][4];  // [mi][reg] per-row running sum of (exp(logit_neg)-1)
  #pragma unroll
  for (int mi = 0; mi < 2; ++mi)
    #pragma unroll
    for (int r = 0; r < 4; ++r) Ssum[mi][r] = 0.0f;

  #pragma unroll 2
  for (int st = 0; st < NSUB; ++st) {
    const unsigned short* cb = L[st & 1];  // current B buffer

    f32x4 acc[2][4];
    const f32x4 z4 = {0.f, 0.f, 0.f, 0.f};
    #pragma unroll
    for (int mi = 0; mi < 2; ++mi)
      #pragma unroll
      for (int ni = 0; ni < 4; ++ni) acc[mi][ni] = z4;

    #pragma unroll
    for (int ks = 0; ks < 4; ++ks) {
      short8 bf[4];
      #pragma unroll
      for (int ni = 0; ni < 4; ++ni) {
        int row = ni * 16 + r16;  // 0..63
        int slot = (ks * 4 + kq) ^ (row & 7);
        bf[ni] = *(const short8*)&cb[row * D_K + slot * 8];
      }
      #pragma unroll
      for (int mi = 0; mi < 2; ++mi)
        #pragma unroll
        for (int ni = 0; ni < 4; ++ni)
          acc[mi][ni] = __builtin_amdgcn_mfma_f32_16x16x32_bf16(
              af[mi][ks], bf[ni], acc[mi][ni], 0, 0, 0);
    }

    // epilogue: logit = (s>m) ? GAMMA*(s^2-m^2) : 0; accumulate exp(logit)-1.
    // For unit-normal embeddings P(s>m) ~ 0.2%, so most reg-quads skip.
    #pragma unroll
    for (int mi = 0; mi < 2; ++mi)
      #pragma unroll
      for (int ni = 0; ni < 4; ++ni) {
        f32x4 v = acc[mi][ni];
        float mx = fmaxf(fmaxf(v[0], v[1]), fmaxf(v[2], v[3]));
        if (__any(mx > MARGIN)) {
          #pragma unroll
          for (int r = 0; r < 4; ++r) {
            float s = v[r];
            float t = fmaf(s, s, -M2);
            float z = (s > MARGIN) ? GAMMA * t : 0.0f;
            Ssum[mi][r] += __expf(z) - 1.0f;  // exactly 0 when z==0
          }
        }
      }

    __syncthreads();  // ends reads of cb; drains next buffer's prefetch

    if (st + 2 < NSUB) {  // prefetch subtile st+2 into the buffer just freed
      const unsigned short* srcB =
          bbf + (size_t)(chunk * CPB + (st + 2) * BN) * D_K;
      unsigned short* dstB = (unsigned short*)L[st & 1];
      #pragma unroll
      for (int it = 0; it < 4; ++it)
        gload_lds16(srcB + stageOff[it], &dstB[(it * 256 + wave * 64) * 8]);
    }
  }

  // each wave owns its 32 rows across the FULL chunk width -> reduce over the
  // 16 column-lanes (same kq group) and write partS directly.
  #pragma unroll
  for (int mi = 0; mi < 2; ++mi)
    #pragma unroll
    for (int r = 0; r < 4; ++r) {
      float v = Ssum[mi][r];
      v += __shfl_xor(v, 1);
      v += __shfl_xor(v, 2);
      v += __shfl_xor(v, 4);
      v += __shfl_xor(v, 8);
      if (r16 == 0)
        partS[(size_t)chunk * B_N + rowBase + wave * 32 + mi * 16 + kq * 4 + r] = v;
    }
}

// ------- kernel 3: per-row finalize + per-block partial sum -------
__global__ __launch_bounds__(256) void rowfin_kernel(
    const float* __restrict__ partS, const float* __restrict__ diag,
    float* __restrict__ bpart) {
  __shared__ float red[4];
  int tid = threadIdx.x, lane = tid & 63, wid = tid >> 6;
  int i = blockIdx.x * 256 + tid;
  float S = 0.0f;
  #pragma unroll
  for (int c = 0; c < NCH; ++c) S += partS[(size_t)c * B_N + i];
  float sd = diag[i];
  float zd = (sd > MARGIN) ? GAMMA * fmaf(sd, sd, -M2) : 0.0f;
  float ed = __expf(zd);
  // sum over off-diagonal of exp(logit_neg) = B + sum(e-1 over all) - e_diag
  float lneg = __logf((float)B_N + S - ed);
  float lpos = -GAMMA * fmaxf((1.0f - MARGIN) - sd, 0.0f) * (sd - MARGIN);
  float x = lpos + lneg;
  float acc = fmaxf(x, 0.0f) + log1pf(__expf(-fabsf(x)));  // softplus
  #pragma unroll
  for (int m = 32; m >= 1; m >>= 1) acc += __shfl_xor(acc, m);
  if (lane == 0) red[wid] = acc;
  __syncthreads();
  if (tid == 0) bpart[blockIdx.x] = red[0] + red[1] + red[2] + red[3];
}

// ---------------- kernel 4: mean over 32 block partials ----------------
__global__ __launch_bounds__(64) void mean_kernel(
    const float* __restrict__ bpart, float* __restrict__ out) {
  int lane = threadIdx.x;
  float v = (lane < 32) ? bpart[lane] : 0.0f;
  #pragma unroll
  for (int m = 32; m >= 1; m >>= 1) v += __shfl_xor(v, m);
  if (lane == 0) out[0] = v * (1.0f / B_N);
}

extern "C" void kernel_launch(void* const* d_in, const int* in_sizes, int n_in,
                              void* d_out, int out_size, void* d_ws, size_t ws_size,
                              hipStream_t stream) {
  const float* a = (const float*)d_in[0];
  const float* b = (const float*)d_in[1];
  float* out = (float*)d_out;

  char* w = (char*)d_ws;
  unsigned short* abf = (unsigned short*)w;                              // 2 MB
  unsigned short* bbf = (unsigned short*)(w + (size_t)B_N * D_K * 2);    // 2 MB
  float* partS = (float*)(w + (size_t)B_N * D_K * 4);                    // 512 KB
  float* diag = partS + (size_t)NCH * B_N;                               // 32 KB
  float* bpart = diag + B_N;                                             // 128 B

  norm_diag_kernel<<<B_N / 4, 256, 0, stream>>>(a, b, abf, bbf, diag);
  simlse_kernel<<<dim3(NCH, B_N / BM), 256, 0, stream>>>(abf, bbf, partS);
  rowfin_kernel<<<NROWBLK, 256, 0, stream>>>(partS, diag, bpart);
  mean_kernel<<<1, 64, 0, stream>>>(bpart, out);
}